// Round 5
// baseline (668.788 us; speedup 1.0000x reference)
//
#include <hip/hip_runtime.h>

// B=8, S=1024, MD=1024, H=16, D=64. SCALE = (64//16)^-0.5 = 0.5.
// Inputs fp32, OUTPUTS fp32. Internal pipeline bf16 MFMA, fp32 accumulate.
// torch .view(B*H,-1,D) = flat row-major reinterpretation: attention over
// [G=128][T=1024][D=64] with flat pointer math.
//
// R4->R5: LDS-granule model (16KB granules, ~128KB pool) explains occupancy
// pinning across R1-R4; residency is causal (R4: 8->4 waves/CU = +25% dur).
// Attention rebuilt as TWO wave-independent passes:
//   attn_ctx:  1 wave = 1 (head, t-tile); s in 8 chunks of 128; exact online
//              accumulation (no max-sub => no rescale); 4.3KB strip/wave;
//              zero barriers; 2048 blocks; rsum wave-local.
//   attn_post: recompute QK^T with h innermost; sig in 16 regs/lane;
//              zero LDS; zero barriers; 2048 blocks.
// All MFMA fragment layouts copied verbatim from the R1-verified kernel.

typedef __attribute__((ext_vector_type(8))) short bf16x8;
typedef __attribute__((ext_vector_type(4))) float f32x4;

static __device__ __forceinline__ short f2bf(float f) {
  union { float f; unsigned u; } v; v.f = f;
  unsigned lsb = (v.u >> 16) & 1u;
  v.u += 0x7fffu + lsb;
  return (short)(v.u >> 16);
}

// round-half-up bf16 (2 ops); fine for positive e^x values
static __device__ __forceinline__ short f2bf_rhu(float f) {
  union { float f; unsigned u; } v; v.f = f;
  v.u += 0x8000u;
  return (short)(v.u >> 16);
}

// hardware 2^x
static __device__ __forceinline__ float exp2_hw(float x) {
  float r;
  asm("v_exp_f32 %0, %1" : "=v"(r) : "v"(x));
  return r;
}

#define L2E_HALF 0.72134752f   /* 0.5 * log2(e) : e^(score*0.5) = 2^(score*this) */

// async global->LDS, 16B per lane; LDS dest = wave-uniform base + lane*16
#define GLDS16(gp, lp) __builtin_amdgcn_global_load_lds( \
    (const __attribute__((address_space(1))) void*)(gp), \
    (__attribute__((address_space(3))) void*)(lp), 16, 0, 0)

struct Ptr4 { const float* s[4]; short* d[4]; };
struct Ptr3 { const float* s[3]; short* d[3]; };
struct QkvArgs { const short* A[3]; const short* B[3]; const float* bias[3]; short* C[3]; };

// ---------- fp32 W[k][n] -> bf16 WT[n][k], 64x64 tiles; z selects matrix ----
__global__ __launch_bounds__(256) void convt4(Ptr4 a)
{
  const float* __restrict__ src = a.s[blockIdx.z];
  short* __restrict__ dst = a.d[blockIdx.z];
  __shared__ float T[64][65];
  const int tid = threadIdx.x;
  const int c0 = blockIdx.x * 64, r0 = blockIdx.y * 64;
  {
    const int rr = tid >> 4, cc = (tid & 15) * 4;
    for (int i = 0; i < 4; ++i) {
      int row = rr + i * 16;
      const float4 v = *(const float4*)(src + (size_t)(r0 + row) * 1024 + c0 + cc);
      T[row][cc] = v.x; T[row][cc + 1] = v.y; T[row][cc + 2] = v.z; T[row][cc + 3] = v.w;
    }
  }
  __syncthreads();
  {
    const int rr = tid >> 3, cc = (tid & 7) * 8;
    for (int i = 0; i < 2; ++i) {
      int row = rr + i * 32;             // dst row within tile (= src col)
      bf16x8 v;
      for (int j = 0; j < 8; ++j) v[j] = f2bf(T[cc + j][row]);
      *(bf16x8*)(dst + (size_t)(c0 + row) * 1024 + r0 + cc) = v;
    }
  }
}

// ---------- fp32 -> bf16 elementwise; z selects tensor ----------
__global__ __launch_bounds__(256) void cvt3(Ptr3 a)
{
  const float* __restrict__ src = a.s[blockIdx.z];
  short* __restrict__ dst = a.d[blockIdx.z];
  const size_t i = ((size_t)blockIdx.x * 256 + threadIdx.x) * 8;
  const float4 v0 = *(const float4*)(src + i);
  const float4 v1 = *(const float4*)(src + i + 4);
  bf16x8 o;
  o[0] = f2bf(v0.x); o[1] = f2bf(v0.y); o[2] = f2bf(v0.z); o[3] = f2bf(v0.w);
  o[4] = f2bf(v1.x); o[5] = f2bf(v1.y); o[6] = f2bf(v1.z); o[7] = f2bf(v1.w);
  *(bf16x8*)(dst + i) = o;
}

// ---------- per-g 64x64 bf16 tile transpose: V[g][t][d] -> VpT[g][d][t] ----
__global__ __launch_bounds__(256) void transp_v(
    const short* __restrict__ src, short* __restrict__ dst)
{
  __shared__ short T[64][72];
  const int g = blockIdx.y, t0 = blockIdx.x * 64;
  const short* s = src + (size_t)g * 65536 + (size_t)t0 * 64;
  short* d = dst + (size_t)g * 65536 + t0;
  const int r = threadIdx.x >> 3, c = (threadIdx.x & 7) * 8;
  for (int i = 0; i < 2; ++i) {
    bf16x8 v = *(const bf16x8*)(s + (size_t)(r + i * 32) * 64 + c);
    *(bf16x8*)(&T[r + i * 32][c]) = v;
  }
  __syncthreads();
  for (int i = 0; i < 2; ++i) {
    int dr = r + i * 32;                 // d index
    bf16x8 v;
    for (int j = 0; j < 8; ++j) v[j] = T[c + j][dr];
    *(bf16x8*)(d + (size_t)dr * 1024 + c) = v;
  }
}

// ---------- GEMM body: C[8192,1024] = A[8192,1024](bf16) * BT[1024,1024]^T + bias
static __device__ __forceinline__ void gemm_body(
    const short* __restrict__ A, const short* __restrict__ BT,
    const float* __restrict__ bias, void* __restrict__ Cp, int mode)
{
  __shared__ short As[128 * 64];
  __shared__ short Bs[128 * 64];
  const int K = 1024, N = 1024;
  const int tid = threadIdx.x;
  const int lane = tid & 63, wave = tid >> 6;
  const int quad = lane >> 4, l16 = lane & 15;
  const int wm = (wave & 1) * 64, wn = (wave >> 1) * 64;
  const int bm = blockIdx.x * 128, bn = blockIdx.y * 128;

  f32x4 acc[4][4] = {};

  const int s_row = tid >> 3;            // 0..31
  const int s_col = (tid & 7) * 8;       // 0..56 (shorts)
  const int lds_base = wave * 512;       // wave-uniform (shorts)

  for (int k0 = 0; k0 < K; k0 += 64) {
    for (int i = 0; i < 4; ++i) {
      int row = s_row + i * 32;
      GLDS16(A + (size_t)(bm + row) * K + k0 + s_col, &As[i * 2048 + lds_base]);
      GLDS16(BT + (size_t)(bn + row) * K + k0 + s_col, &Bs[i * 2048 + lds_base]);
    }
    __syncthreads();
    for (int ks = 0; ks < 2; ++ks) {
      bf16x8 af[4], bfr[4];
      for (int mi = 0; mi < 4; ++mi)
        af[mi] = *(const bf16x8*)(&As[(wm + mi * 16 + l16) * 64 + ks * 32 + quad * 8]);
      for (int ni = 0; ni < 4; ++ni)
        bfr[ni] = *(const bf16x8*)(&Bs[(wn + ni * 16 + l16) * 64 + ks * 32 + quad * 8]);
      for (int mi = 0; mi < 4; ++mi)
        for (int ni = 0; ni < 4; ++ni)
          acc[mi][ni] = __builtin_amdgcn_mfma_f32_16x16x32_bf16(af[mi], bfr[ni], acc[mi][ni], 0, 0, 0);
    }
    __syncthreads();
  }

  for (int ni = 0; ni < 4; ++ni) {
    int col = bn + wn + ni * 16 + l16;
    float bv = bias[col];
    for (int mi = 0; mi < 4; ++mi) {
      int row0 = bm + wm + mi * 16 + quad * 4;   // C row = quad*4+reg
      for (int r = 0; r < 4; ++r) {
        int row = row0 + r;
        float fv = acc[mi][ni][r] + bv;
        if (mode == 2) ((float*)Cp)[(size_t)row * N + col] = fv;
        else           ((short*)Cp)[(size_t)row * N + col] = f2bf(fv);
      }
    }
  }
}

__global__ __launch_bounds__(256) void gemm_bt16(
    const short* __restrict__ A, const short* __restrict__ BT,
    const float* __restrict__ bias, void* __restrict__ Cp, int mode)
{
  gemm_body(A, BT, bias, Cp, mode);
}

// combined Q/K/V projection: grid.z selects which GEMM
__global__ __launch_bounds__(256) void gemm_qkv(QkvArgs a)
{
  const int z = blockIdx.z;
  gemm_body(a.A[z], a.B[z], a.bias[z], a.C[z], 0);
}

// ---------- PASS 1: ctx. One wave = one (g, t-tile) unit, zero barriers ----
// s processed in 8 chunks of 128; exact online accumulation (no max-sub =>
// no rescaling). e^x <= ~4e5 (scores*0.5 ~ N(0,16)) -- f32/bf16 safe.
// Fragment conventions identical to the R1-verified kernel:
//   QK: A=Q[t][d], B=K[s][d] -> D[t=quad*4+r][s=tile*16+l16]
//   PV: A=P[t][s] (from strip), B=V^T[d][s] -> D[t=quad*4+r][d=ni*16+l16]
__global__ __launch_bounds__(256, 4) void attn_ctx(
    const short* __restrict__ Qp, const short* __restrict__ Kp,
    const short* __restrict__ VpT,               // [g][d][t]
    short* __restrict__ ctx)                     // [g][t][d] bf16
{
  __shared__ short strip[4][16][136];            // 17408 B; wave-private strips
  const int tid = threadIdx.x;
  const int wave = tid >> 6, lane = tid & 63;
  const int quad = lane >> 4, l16 = lane & 15;
  const int unit = blockIdx.x * 4 + wave;        // 0..8191
  const int g = unit >> 6;
  const int t0 = (unit & 63) * 16;

  const short* Qg = Qp + (size_t)g * 65536;
  const short* Kg = Kp + (size_t)g * 65536;
  const short* Vg = VpT + (size_t)g * 65536;

  bf16x8 aq0 = *(const bf16x8*)(Qg + (t0 + l16) * 64 + quad * 8);
  bf16x8 aq1 = *(const bf16x8*)(Qg + (t0 + l16) * 64 + 32 + quad * 8);

  float rsum[4] = {0.f, 0.f, 0.f, 0.f};
  f32x4 cacc[4] = {};
  for (int c = 0; c < 8; ++c) {
    const int s0 = c * 128;
    for (int tile = 0; tile < 8; ++tile) {
      int s = s0 + tile * 16;
      bf16x8 bk0 = *(const bf16x8*)(Kg + (s + l16) * 64 + quad * 8);
      bf16x8 bk1 = *(const bf16x8*)(Kg + (s + l16) * 64 + 32 + quad * 8);
      f32x4 cc = {0.f, 0.f, 0.f, 0.f};
      cc = __builtin_amdgcn_mfma_f32_16x16x32_bf16(aq0, bk0, cc, 0, 0, 0);
      cc = __builtin_amdgcn_mfma_f32_16x16x32_bf16(aq1, bk1, cc, 0, 0, 0);
      for (int r = 0; r < 4; ++r) {
        float e = exp2_hw(cc[r] * L2E_HALF);     // e^(score*0.5), UNNORMALIZED
        rsum[r] += e;
        strip[wave][quad * 4 + r][tile * 16 + l16] = f2bf_rhu(e);
      }
    }
    // PV accumulate for this chunk (wave-local LDS; compiler orders RAW/WAR)
    for (int ks = 0; ks < 4; ++ks) {
      bf16x8 ap = *(const bf16x8*)(&strip[wave][l16][ks * 32 + quad * 8]);
      for (int ni = 0; ni < 4; ++ni) {
        bf16x8 bv = *(const bf16x8*)(Vg + (ni * 16 + l16) * 1024 + s0 + ks * 32 + quad * 8);
        cacc[ni] = __builtin_amdgcn_mfma_f32_16x16x32_bf16(ap, bv, cacc[ni], 0, 0, 0);
      }
    }
  }
  // rsum: reduce across the 16 l16-lanes of each quad group (wave-local)
  for (int r = 0; r < 4; ++r)
    for (int m = 1; m < 16; m <<= 1) rsum[r] += __shfl_xor(rsum[r], m, 64);
  short* cg = ctx + (size_t)g * 65536 + t0 * 64;
  for (int r = 0; r < 4; ++r) {
    float iv = __builtin_amdgcn_rcpf(rsum[r]);
    for (int ni = 0; ni < 4; ++ni)
      cg[(quad * 4 + r) * 64 + ni * 16 + l16] = f2bf(cacc[ni][r] * iv);
  }
}

// ---------- PASS 2: attn_post. One wave = one (b, t16, s64) unit ----------
// Recomputes QK^T with h innermost; sig accumulates in 16 regs/lane.
// Zero LDS, zero barriers.
__global__ __launch_bounds__(256, 4) void attn_post_k(
    const short* __restrict__ Qp, const short* __restrict__ Kp,
    float* __restrict__ attn_post)               // [b][t][s] fp32
{
  const int tid = threadIdx.x;
  const int wave = tid >> 6, lane = tid & 63;
  const int quad = lane >> 4, l16 = lane & 15;
  const int unit = blockIdx.x * 4 + wave;        // 0..8191
  const int b = unit >> 10;
  const int t0 = ((unit >> 4) & 63) * 16;
  const int s0 = (unit & 15) * 64;

  f32x4 sig[4] = {};                             // [s-subtile][r]
  for (int h = 0; h < 16; ++h) {
    const int g = b * 16 + h;
    const short* Qg = Qp + (size_t)g * 65536;
    const short* Kg = Kp + (size_t)g * 65536;
    bf16x8 aq0 = *(const bf16x8*)(Qg + (t0 + l16) * 64 + quad * 8);
    bf16x8 aq1 = *(const bf16x8*)(Qg + (t0 + l16) * 64 + 32 + quad * 8);
    for (int st = 0; st < 4; ++st) {
      int s = s0 + st * 16;
      bf16x8 bk0 = *(const bf16x8*)(Kg + (s + l16) * 64 + quad * 8);
      bf16x8 bk1 = *(const bf16x8*)(Kg + (s + l16) * 64 + 32 + quad * 8);
      f32x4 cc = {0.f, 0.f, 0.f, 0.f};
      cc = __builtin_amdgcn_mfma_f32_16x16x32_bf16(aq0, bk0, cc, 0, 0, 0);
      cc = __builtin_amdgcn_mfma_f32_16x16x32_bf16(aq1, bk1, cc, 0, 0, 0);
      for (int r = 0; r < 4; ++r) {
        float e = exp2_hw(cc[r] * L2E_HALF);
        sig[st][r] += e * __builtin_amdgcn_rcpf(1.f + e);   // sigmoid(score*0.5)
      }
    }
  }
  float* ap = attn_post + (size_t)b * 1048576 + (size_t)t0 * 1024 + s0;
  for (int st = 0; st < 4; ++st)
    for (int r = 0; r < 4; ++r)
      ap[(quad * 4 + r) * 1024 + st * 16 + l16] = sig[st][r] * 0.0625f;
}

extern "C" void kernel_launch(void* const* d_in, const int* in_sizes, int n_in,
                              void* d_out, int out_size, void* d_ws, size_t ws_size,
                              hipStream_t stream) {
  const float* query = (const float*)d_in[0];
  const float* key   = (const float*)d_in[1];
  const float* value = (const float*)d_in[2];
  const float* Wq = (const float*)d_in[3]; const float* bq = (const float*)d_in[4];
  const float* Wk = (const float*)d_in[5]; const float* bk = (const float*)d_in[6];
  const float* Wv = (const float*)d_in[7]; const float* bv = (const float*)d_in[8];
  const float* Wo = (const float*)d_in[9]; const float* bo = (const float*)d_in[10];

  float* out0 = (float*)d_out;              // [8,1024,1024] fp32
  float* attn_post = out0 + (8u << 20);     // [8,1024,1024] fp32

  // common workspace head: 4 x 1M weightT + 3 x 8M (Qp,Kp,VpT)
  short* WqT = (short*)d_ws;
  short* WkT = WqT + (1u << 20);
  short* WvT = WkT + (1u << 20);
  short* WoT = WvT + (1u << 20);
  short* Qp  = WoT + (1u << 20);
  short* Kp  = Qp + (8u << 20);
  short* VpT = Kp + (8u << 20);

  dim3 blk(256);
  const size_t NEED_BIG = (size_t)(60u << 20) * 2;   // 120 MiB

  convt4<<<dim3(16, 16, 4), blk, 0, stream>>>(
      Ptr4{{Wq, Wk, Wv, Wo}, {WqT, WkT, WvT, WoT}});

  short* ctx;
  if (ws_size >= NEED_BIG) {
    // big layout: + Xq,Xk,Xv (3 x 8M) + Vflat (8M) = 60M shorts total
    short* Xq = VpT + (8u << 20);
    short* Xk = Xq + (8u << 20);
    short* Xv = Xk + (8u << 20);
    short* Vflat = Xv + (8u << 20);
    ctx = Xq;                                      // dead after qkv GEMM

    cvt3<<<dim3(4096, 1, 3), blk, 0, stream>>>(Ptr3{{query, key, value}, {Xq, Xk, Xv}});
    gemm_qkv<<<dim3(64, 8, 3), blk, 0, stream>>>(
        QkvArgs{{Xq, Xk, Xv}, {WqT, WkT, WvT}, {bq, bk, bv}, {Qp, Kp, Vflat}});
    transp_v<<<dim3(16, 128), blk, 0, stream>>>(Vflat, VpT);
  } else {
    // small layout (88 MB, proven): Xin (8M) + Vflat (8M), sequential
    short* Xin = VpT + (8u << 20);
    short* Vflat = Xin + (8u << 20);
    ctx = Xin;

    cvt3<<<dim3(4096, 1, 1), blk, 0, stream>>>(Ptr3{{query, query, query}, {Xin, Xin, Xin}});
    gemm_bt16<<<dim3(64, 8), blk, 0, stream>>>(Xin, WqT, bq, Qp, 0);
    cvt3<<<dim3(4096, 1, 1), blk, 0, stream>>>(Ptr3{{key, key, key}, {Xin, Xin, Xin}});
    gemm_bt16<<<dim3(64, 8), blk, 0, stream>>>(Xin, WkT, bk, Kp, 0);
    cvt3<<<dim3(4096, 1, 1), blk, 0, stream>>>(Ptr3{{value, value, value}, {Xin, Xin, Xin}});
    gemm_bt16<<<dim3(64, 8), blk, 0, stream>>>(Xin, WvT, bv, Vflat, 0);
    transp_v<<<dim3(16, 128), blk, 0, stream>>>(Vflat, VpT);
  }

  attn_ctx<<<dim3(2048), blk, 0, stream>>>(Qp, Kp, VpT, ctx);
  attn_post_k<<<dim3(2048), blk, 0, stream>>>(Qp, Kp, attn_post);
  gemm_bt16<<<dim3(64, 8), blk, 0, stream>>>(ctx, WoT, bo, out0, 2);
}

// Round 6
// 528.445 us; speedup vs baseline: 1.2656x; 1.2656x over previous
//
#include <hip/hip_runtime.h>

// B=8, S=1024, MD=1024, H=16, D=64. SCALE = (64//16)^-0.5 = 0.5.
// Inputs fp32, OUTPUTS fp32. Internal pipeline bf16 MFMA, fp32 accumulate.
// torch .view(B*H,-1,D) = flat row-major reinterpretation: attention over
// [G=128][T=1024][D=64] with flat pointer math.
//
// R5->R6: attn is per-wave memory-latency serialized (R5: occ 46%, ALL
// pipes <10%; compiler kept VGPR=56, ~1 tile of loads in flight). Revert
// to the R1 fused topology (512 blocks, 16 heads/block, both outputs, no
// recompute pass) and add explicit software pipelining at constant
// residency: K prefetch 4-deep (rotating regs, full unroll), V/P prefetch
// 2-deep in PV. Registers ~104->~175 (free: LDS caps blocks/CU at 2).

typedef __attribute__((ext_vector_type(8))) short bf16x8;
typedef __attribute__((ext_vector_type(4))) float f32x4;

static __device__ __forceinline__ short f2bf(float f) {
  union { float f; unsigned u; } v; v.f = f;
  unsigned lsb = (v.u >> 16) & 1u;
  v.u += 0x7fffu + lsb;
  return (short)(v.u >> 16);
}

// round-half-up bf16 (2 ops); fine for positive e^x values
static __device__ __forceinline__ short f2bf_rhu(float f) {
  union { float f; unsigned u; } v; v.f = f;
  v.u += 0x8000u;
  return (short)(v.u >> 16);
}

// hardware 2^x
static __device__ __forceinline__ float exp2_hw(float x) {
  float r;
  asm("v_exp_f32 %0, %1" : "=v"(r) : "v"(x));
  return r;
}

#define L2E_HALF 0.72134752f   /* 0.5 * log2(e) : e^(score*0.5) = 2^(score*this) */

// async global->LDS, 16B per lane; LDS dest = wave-uniform base + lane*16
#define GLDS16(gp, lp) __builtin_amdgcn_global_load_lds( \
    (const __attribute__((address_space(1))) void*)(gp), \
    (__attribute__((address_space(3))) void*)(lp), 16, 0, 0)

struct Ptr4 { const float* s[4]; short* d[4]; };
struct Ptr3 { const float* s[3]; short* d[3]; };
struct QkvArgs { const short* A[3]; const short* B[3]; const float* bias[3]; short* C[3]; };

// ---------- fp32 W[k][n] -> bf16 WT[n][k], 64x64 tiles; z selects matrix ----
__global__ __launch_bounds__(256) void convt4(Ptr4 a)
{
  const float* __restrict__ src = a.s[blockIdx.z];
  short* __restrict__ dst = a.d[blockIdx.z];
  __shared__ float T[64][65];
  const int tid = threadIdx.x;
  const int c0 = blockIdx.x * 64, r0 = blockIdx.y * 64;
  {
    const int rr = tid >> 4, cc = (tid & 15) * 4;
    for (int i = 0; i < 4; ++i) {
      int row = rr + i * 16;
      const float4 v = *(const float4*)(src + (size_t)(r0 + row) * 1024 + c0 + cc);
      T[row][cc] = v.x; T[row][cc + 1] = v.y; T[row][cc + 2] = v.z; T[row][cc + 3] = v.w;
    }
  }
  __syncthreads();
  {
    const int rr = tid >> 3, cc = (tid & 7) * 8;
    for (int i = 0; i < 2; ++i) {
      int row = rr + i * 32;             // dst row within tile (= src col)
      bf16x8 v;
      for (int j = 0; j < 8; ++j) v[j] = f2bf(T[cc + j][row]);
      *(bf16x8*)(dst + (size_t)(c0 + row) * 1024 + r0 + cc) = v;
    }
  }
}

// ---------- fp32 -> bf16 elementwise; z selects tensor ----------
__global__ __launch_bounds__(256) void cvt3(Ptr3 a)
{
  const float* __restrict__ src = a.s[blockIdx.z];
  short* __restrict__ dst = a.d[blockIdx.z];
  const size_t i = ((size_t)blockIdx.x * 256 + threadIdx.x) * 8;
  const float4 v0 = *(const float4*)(src + i);
  const float4 v1 = *(const float4*)(src + i + 4);
  bf16x8 o;
  o[0] = f2bf(v0.x); o[1] = f2bf(v0.y); o[2] = f2bf(v0.z); o[3] = f2bf(v0.w);
  o[4] = f2bf(v1.x); o[5] = f2bf(v1.y); o[6] = f2bf(v1.z); o[7] = f2bf(v1.w);
  *(bf16x8*)(dst + i) = o;
}

// ---------- per-g 64x64 bf16 tile transpose: V[g][t][d] -> VpT[g][d][t] ----
__global__ __launch_bounds__(256) void transp_v(
    const short* __restrict__ src, short* __restrict__ dst)
{
  __shared__ short T[64][72];
  const int g = blockIdx.y, t0 = blockIdx.x * 64;
  const short* s = src + (size_t)g * 65536 + (size_t)t0 * 64;
  short* d = dst + (size_t)g * 65536 + t0;
  const int r = threadIdx.x >> 3, c = (threadIdx.x & 7) * 8;
  for (int i = 0; i < 2; ++i) {
    bf16x8 v = *(const bf16x8*)(s + (size_t)(r + i * 32) * 64 + c);
    *(bf16x8*)(&T[r + i * 32][c]) = v;
  }
  __syncthreads();
  for (int i = 0; i < 2; ++i) {
    int dr = r + i * 32;                 // d index
    bf16x8 v;
    for (int j = 0; j < 8; ++j) v[j] = T[c + j][dr];
    *(bf16x8*)(d + (size_t)dr * 1024 + c) = v;
  }
}

// ---------- GEMM body: C[8192,1024] = A[8192,1024](bf16) * BT[1024,1024]^T + bias
static __device__ __forceinline__ void gemm_body(
    const short* __restrict__ A, const short* __restrict__ BT,
    const float* __restrict__ bias, void* __restrict__ Cp, int mode)
{
  __shared__ short As[128 * 64];
  __shared__ short Bs[128 * 64];
  const int K = 1024, N = 1024;
  const int tid = threadIdx.x;
  const int lane = tid & 63, wave = tid >> 6;
  const int quad = lane >> 4, l16 = lane & 15;
  const int wm = (wave & 1) * 64, wn = (wave >> 1) * 64;
  const int bm = blockIdx.x * 128, bn = blockIdx.y * 128;

  f32x4 acc[4][4] = {};

  const int s_row = tid >> 3;            // 0..31
  const int s_col = (tid & 7) * 8;       // 0..56 (shorts)
  const int lds_base = wave * 512;       // wave-uniform (shorts)

  for (int k0 = 0; k0 < K; k0 += 64) {
    for (int i = 0; i < 4; ++i) {
      int row = s_row + i * 32;
      GLDS16(A + (size_t)(bm + row) * K + k0 + s_col, &As[i * 2048 + lds_base]);
      GLDS16(BT + (size_t)(bn + row) * K + k0 + s_col, &Bs[i * 2048 + lds_base]);
    }
    __syncthreads();
    for (int ks = 0; ks < 2; ++ks) {
      bf16x8 af[4], bfr[4];
      for (int mi = 0; mi < 4; ++mi)
        af[mi] = *(const bf16x8*)(&As[(wm + mi * 16 + l16) * 64 + ks * 32 + quad * 8]);
      for (int ni = 0; ni < 4; ++ni)
        bfr[ni] = *(const bf16x8*)(&Bs[(wn + ni * 16 + l16) * 64 + ks * 32 + quad * 8]);
      for (int mi = 0; mi < 4; ++mi)
        for (int ni = 0; ni < 4; ++ni)
          acc[mi][ni] = __builtin_amdgcn_mfma_f32_16x16x32_bf16(af[mi], bfr[ni], acc[mi][ni], 0, 0, 0);
    }
    __syncthreads();
  }

  for (int ni = 0; ni < 4; ++ni) {
    int col = bn + wn + ni * 16 + l16;
    float bv = bias[col];
    for (int mi = 0; mi < 4; ++mi) {
      int row0 = bm + wm + mi * 16 + quad * 4;   // C row = quad*4+reg
      for (int r = 0; r < 4; ++r) {
        int row = row0 + r;
        float fv = acc[mi][ni][r] + bv;
        if (mode == 2) ((float*)Cp)[(size_t)row * N + col] = fv;
        else           ((short*)Cp)[(size_t)row * N + col] = f2bf(fv);
      }
    }
  }
}

__global__ __launch_bounds__(256) void gemm_bt16(
    const short* __restrict__ A, const short* __restrict__ BT,
    const float* __restrict__ bias, void* __restrict__ Cp, int mode)
{
  gemm_body(A, BT, bias, Cp, mode);
}

// combined Q/K/V projection: grid.z selects which GEMM
__global__ __launch_bounds__(256) void gemm_qkv(QkvArgs a)
{
  const int z = blockIdx.z;
  gemm_body(a.A[z], a.B[z], a.bias[z], a.C[z], 0);
}

// ---------- fused attention over [G=128,T=1024,D=64] ----------
// R1 topology: block = (b, 16-row t-tile); 4 waves split s into 256-wide
// strips; 16 heads serial; both outputs produced here (no recompute pass).
// NEW: deep register prefetch -- K 4-deep rotating buffers (8 loads in
// flight), V/P 2-deep ping-pong in PV. All buffer indices compile-time
// (full unroll) so arrays stay in registers.
// No max-subtraction: scores ~N(0,16), |x|<~35 => e^x f32/bf16-safe.
__global__ __launch_bounds__(256) void attn_fused5(
    const short* __restrict__ Qp, const short* __restrict__ Kp,
    const short* __restrict__ VpT,               // [g][d][t]
    short* __restrict__ ctx,                     // [g][t][d] flat (bf16)
    float* __restrict__ attn_post)               // [b][t][s] FP32
{
  __shared__ short Plds[16][1032];
  __shared__ float red[16][4];
  __shared__ float ctxred[4][16][64];

  const int tid = threadIdx.x;
  const int wave = tid >> 6, lane = tid & 63;
  const int quad = lane >> 4, l16 = lane & 15;
  const int b = blockIdx.x >> 6;
  const int t0 = (blockIdx.x & 63) * 16;
  const int sbase = wave * 256;

  float sig[16][4] = {};                         // sigmoid acc over heads

  for (int h = 0; h < 16; ++h) {
    const int g = b * 16 + h;
    const short* Qg = Qp + (size_t)g * 65536;
    const short* Kg = Kp + (size_t)g * 65536;
    const short* Vg = VpT + (size_t)g * 65536;

    bf16x8 aq0 = *(const bf16x8*)(Qg + (t0 + l16) * 64 + quad * 8);
    bf16x8 aq1 = *(const bf16x8*)(Qg + (t0 + l16) * 64 + 32 + quad * 8);

    float sc[16][4];                             // holds e^x
    float rsum[4] = {0.f, 0.f, 0.f, 0.f};

    // ---- QK^T score loop: 16 tiles, K prefetched 4 tiles deep ----
    bf16x8 kb0[4], kb1[4];
#pragma unroll
    for (int t = 0; t < 4; ++t) {
      int s = sbase + t * 16;
      kb0[t] = *(const bf16x8*)(Kg + (s + l16) * 64 + quad * 8);
      kb1[t] = *(const bf16x8*)(Kg + (s + l16) * 64 + 32 + quad * 8);
    }
#pragma unroll
    for (int tile = 0; tile < 16; ++tile) {
      const int slot = tile & 3;
      bf16x8 bk0 = kb0[slot], bk1 = kb1[slot];
      if (tile < 12) {
        int s = sbase + (tile + 4) * 16;
        kb0[slot] = *(const bf16x8*)(Kg + (s + l16) * 64 + quad * 8);
        kb1[slot] = *(const bf16x8*)(Kg + (s + l16) * 64 + 32 + quad * 8);
      }
      f32x4 c = {0.f, 0.f, 0.f, 0.f};
      c = __builtin_amdgcn_mfma_f32_16x16x32_bf16(aq0, bk0, c, 0, 0, 0);
      c = __builtin_amdgcn_mfma_f32_16x16x32_bf16(aq1, bk1, c, 0, 0, 0);
#pragma unroll
      for (int r = 0; r < 4; ++r) {
        float e = exp2_hw(c[r] * L2E_HALF);      // e^(score*0.5)
        sc[tile][r] = e;
        rsum[r] += e;
        sig[tile][r] += e * __builtin_amdgcn_rcpf(1.f + e);   // sigmoid
      }
    }
#pragma unroll
    for (int r = 0; r < 4; ++r)
      for (int mask = 1; mask < 16; mask <<= 1) rsum[r] += __shfl_xor(rsum[r], mask, 64);
    if (l16 == 0)
      for (int r = 0; r < 4; ++r) red[quad * 4 + r][wave] = rsum[r];
    __syncthreads();                             // B1
#pragma unroll
    for (int r = 0; r < 4; ++r) {
      int row = quad * 4 + r;
      float s4 = red[row][0] + red[row][1] + red[row][2] + red[row][3];
      float inv = __builtin_amdgcn_rcpf(s4);
#pragma unroll
      for (int tile = 0; tile < 16; ++tile)
        Plds[row][sbase + tile * 16 + l16] = f2bf_rhu(sc[tile][r] * inv);
    }

    // ---- PV: 8 k-slices, V and P prefetched one slice ahead ----
    f32x4 cacc[4] = {};
    bf16x8 apb[2], vb[2][4];
    apb[0] = *(const bf16x8*)(&Plds[l16][sbase + quad * 8]);
#pragma unroll
    for (int ni = 0; ni < 4; ++ni)
      vb[0][ni] = *(const bf16x8*)(Vg + (ni * 16 + l16) * 1024 + sbase + quad * 8);
#pragma unroll
    for (int ks = 0; ks < 8; ++ks) {
      const int cur = ks & 1, nxt = cur ^ 1;
      if (ks < 7) {
        apb[nxt] = *(const bf16x8*)(&Plds[l16][sbase + (ks + 1) * 32 + quad * 8]);
#pragma unroll
        for (int ni = 0; ni < 4; ++ni)
          vb[nxt][ni] = *(const bf16x8*)(Vg + (ni * 16 + l16) * 1024 + sbase + (ks + 1) * 32 + quad * 8);
      }
#pragma unroll
      for (int ni = 0; ni < 4; ++ni)
        cacc[ni] = __builtin_amdgcn_mfma_f32_16x16x32_bf16(apb[cur], vb[cur][ni], cacc[ni], 0, 0, 0);
    }

    for (int ni = 0; ni < 4; ++ni)
      for (int r = 0; r < 4; ++r)
        ctxred[wave][quad * 4 + r][ni * 16 + l16] = cacc[ni][r];
    __syncthreads();                             // B2
    short* ctxg = ctx + (size_t)g * 65536 + t0 * 64;
    for (int e = tid; e < 1024; e += 256) {
      int t = e >> 6, dd = e & 63;
      float v = ctxred[0][t][dd] + ctxred[1][t][dd] + ctxred[2][t][dd] + ctxred[3][t][dd];
      ctxg[t * 64 + dd] = f2bf(v);
    }
    // red/Plds/ctxred for head h+1 are written only after h+1's B1 -> safe.
  }

  float* ap_out = attn_post + (size_t)b * 1048576 + (size_t)t0 * 1024;
  for (int tile = 0; tile < 16; ++tile)
    for (int r = 0; r < 4; ++r)
      ap_out[(quad * 4 + r) * 1024 + sbase + tile * 16 + l16] = sig[tile][r] * 0.0625f;
}

extern "C" void kernel_launch(void* const* d_in, const int* in_sizes, int n_in,
                              void* d_out, int out_size, void* d_ws, size_t ws_size,
                              hipStream_t stream) {
  const float* query = (const float*)d_in[0];
  const float* key   = (const float*)d_in[1];
  const float* value = (const float*)d_in[2];
  const float* Wq = (const float*)d_in[3]; const float* bq = (const float*)d_in[4];
  const float* Wk = (const float*)d_in[5]; const float* bk = (const float*)d_in[6];
  const float* Wv = (const float*)d_in[7]; const float* bv = (const float*)d_in[8];
  const float* Wo = (const float*)d_in[9]; const float* bo = (const float*)d_in[10];

  float* out0 = (float*)d_out;              // [8,1024,1024] fp32
  float* attn_post = out0 + (8u << 20);     // [8,1024,1024] fp32

  // common workspace head: 4 x 1M weightT + 3 x 8M (Qp,Kp,VpT)
  short* WqT = (short*)d_ws;
  short* WkT = WqT + (1u << 20);
  short* WvT = WkT + (1u << 20);
  short* WoT = WvT + (1u << 20);
  short* Qp  = WoT + (1u << 20);
  short* Kp  = Qp + (8u << 20);
  short* VpT = Kp + (8u << 20);

  dim3 blk(256);
  const size_t NEED_BIG = (size_t)(60u << 20) * 2;   // 120 MiB

  convt4<<<dim3(16, 16, 4), blk, 0, stream>>>(
      Ptr4{{Wq, Wk, Wv, Wo}, {WqT, WkT, WvT, WoT}});

  short* ctx;
  if (ws_size >= NEED_BIG) {
    // big layout: + Xq,Xk,Xv (3 x 8M) + Vflat (8M) = 60M shorts total
    short* Xq = VpT + (8u << 20);
    short* Xk = Xq + (8u << 20);
    short* Xv = Xk + (8u << 20);
    short* Vflat = Xv + (8u << 20);
    ctx = Xq;                                      // dead after qkv GEMM

    cvt3<<<dim3(4096, 1, 3), blk, 0, stream>>>(Ptr3{{query, key, value}, {Xq, Xk, Xv}});
    gemm_qkv<<<dim3(64, 8, 3), blk, 0, stream>>>(
        QkvArgs{{Xq, Xk, Xv}, {WqT, WkT, WvT}, {bq, bk, bv}, {Qp, Kp, Vflat}});
    transp_v<<<dim3(16, 128), blk, 0, stream>>>(Vflat, VpT);
  } else {
    // small layout (88 MB, proven): Xin (8M) + Vflat (8M), sequential
    short* Xin = VpT + (8u << 20);
    short* Vflat = Xin + (8u << 20);
    ctx = Xin;

    cvt3<<<dim3(4096, 1, 1), blk, 0, stream>>>(Ptr3{{query, query, query}, {Xin, Xin, Xin}});
    gemm_bt16<<<dim3(64, 8), blk, 0, stream>>>(Xin, WqT, bq, Qp, 0);
    cvt3<<<dim3(4096, 1, 1), blk, 0, stream>>>(Ptr3{{key, key, key}, {Xin, Xin, Xin}});
    gemm_bt16<<<dim3(64, 8), blk, 0, stream>>>(Xin, WkT, bk, Kp, 0);
    cvt3<<<dim3(4096, 1, 1), blk, 0, stream>>>(Ptr3{{value, value, value}, {Xin, Xin, Xin}});
    gemm_bt16<<<dim3(64, 8), blk, 0, stream>>>(Xin, WvT, bv, Vflat, 0);
    transp_v<<<dim3(16, 128), blk, 0, stream>>>(Vflat, VpT);
  }

  attn_fused5<<<dim3(512), blk, 0, stream>>>(Qp, Kp, VpT, ctx, attn_post);
  gemm_bt16<<<dim3(64, 8), blk, 0, stream>>>(ctx, WoT, bo, out0, 2);
}

// Round 7
// 526.741 us; speedup vs baseline: 1.2697x; 1.0032x over previous
//
#include <hip/hip_runtime.h>

// B=8, S=1024, MD=1024, H=16, D=64. SCALE = (64//16)^-0.5 = 0.5.
// Inputs fp32, OUTPUTS fp32. Internal pipeline bf16 MFMA, fp32 accumulate.
// torch .view(B*H,-1,D) = flat row-major reinterpretation: attention over
// [G=128][T=1024][D=64] with flat pointer math.
//
// R6->R7: FETCH_SIZE 139MB vs 48MB working set (2.9x read amplification at
// 9% HBM BW) = L2 locality failure. Blocks [64b,64b+63] share batch b's
// 6MB (384KB per head-iteration), but HW round-robin dispatch spreads them
// over all 8 XCDs -> every 4MB L2 streams all 48MB. Since 512 blocks =
// 8 XCDs x 64 and B=8, remap work = (orig&7)*64 + (orig>>3): XCD i runs
// exactly batch i's 64 blocks; per-head 384KB becomes L2-resident.
// (T1 XCD-swizzle; bijective since 512%8==0. Only attn changed this round.)

typedef __attribute__((ext_vector_type(8))) short bf16x8;
typedef __attribute__((ext_vector_type(4))) float f32x4;

static __device__ __forceinline__ short f2bf(float f) {
  union { float f; unsigned u; } v; v.f = f;
  unsigned lsb = (v.u >> 16) & 1u;
  v.u += 0x7fffu + lsb;
  return (short)(v.u >> 16);
}

// round-half-up bf16 (2 ops); fine for positive e^x values
static __device__ __forceinline__ short f2bf_rhu(float f) {
  union { float f; unsigned u; } v; v.f = f;
  v.u += 0x8000u;
  return (short)(v.u >> 16);
}

// hardware 2^x
static __device__ __forceinline__ float exp2_hw(float x) {
  float r;
  asm("v_exp_f32 %0, %1" : "=v"(r) : "v"(x));
  return r;
}

#define L2E_HALF 0.72134752f   /* 0.5 * log2(e) : e^(score*0.5) = 2^(score*this) */

// async global->LDS, 16B per lane; LDS dest = wave-uniform base + lane*16
#define GLDS16(gp, lp) __builtin_amdgcn_global_load_lds( \
    (const __attribute__((address_space(1))) void*)(gp), \
    (__attribute__((address_space(3))) void*)(lp), 16, 0, 0)

struct Ptr4 { const float* s[4]; short* d[4]; };
struct Ptr3 { const float* s[3]; short* d[3]; };
struct QkvArgs { const short* A[3]; const short* B[3]; const float* bias[3]; short* C[3]; };

// ---------- fp32 W[k][n] -> bf16 WT[n][k], 64x64 tiles; z selects matrix ----
__global__ __launch_bounds__(256) void convt4(Ptr4 a)
{
  const float* __restrict__ src = a.s[blockIdx.z];
  short* __restrict__ dst = a.d[blockIdx.z];
  __shared__ float T[64][65];
  const int tid = threadIdx.x;
  const int c0 = blockIdx.x * 64, r0 = blockIdx.y * 64;
  {
    const int rr = tid >> 4, cc = (tid & 15) * 4;
    for (int i = 0; i < 4; ++i) {
      int row = rr + i * 16;
      const float4 v = *(const float4*)(src + (size_t)(r0 + row) * 1024 + c0 + cc);
      T[row][cc] = v.x; T[row][cc + 1] = v.y; T[row][cc + 2] = v.z; T[row][cc + 3] = v.w;
    }
  }
  __syncthreads();
  {
    const int rr = tid >> 3, cc = (tid & 7) * 8;
    for (int i = 0; i < 2; ++i) {
      int row = rr + i * 32;             // dst row within tile (= src col)
      bf16x8 v;
      for (int j = 0; j < 8; ++j) v[j] = f2bf(T[cc + j][row]);
      *(bf16x8*)(dst + (size_t)(c0 + row) * 1024 + r0 + cc) = v;
    }
  }
}

// ---------- fp32 -> bf16 elementwise; z selects tensor ----------
__global__ __launch_bounds__(256) void cvt3(Ptr3 a)
{
  const float* __restrict__ src = a.s[blockIdx.z];
  short* __restrict__ dst = a.d[blockIdx.z];
  const size_t i = ((size_t)blockIdx.x * 256 + threadIdx.x) * 8;
  const float4 v0 = *(const float4*)(src + i);
  const float4 v1 = *(const float4*)(src + i + 4);
  bf16x8 o;
  o[0] = f2bf(v0.x); o[1] = f2bf(v0.y); o[2] = f2bf(v0.z); o[3] = f2bf(v0.w);
  o[4] = f2bf(v1.x); o[5] = f2bf(v1.y); o[6] = f2bf(v1.z); o[7] = f2bf(v1.w);
  *(bf16x8*)(dst + i) = o;
}

// ---------- per-g 64x64 bf16 tile transpose: V[g][t][d] -> VpT[g][d][t] ----
__global__ __launch_bounds__(256) void transp_v(
    const short* __restrict__ src, short* __restrict__ dst)
{
  __shared__ short T[64][72];
  const int g = blockIdx.y, t0 = blockIdx.x * 64;
  const short* s = src + (size_t)g * 65536 + (size_t)t0 * 64;
  short* d = dst + (size_t)g * 65536 + t0;
  const int r = threadIdx.x >> 3, c = (threadIdx.x & 7) * 8;
  for (int i = 0; i < 2; ++i) {
    bf16x8 v = *(const bf16x8*)(s + (size_t)(r + i * 32) * 64 + c);
    *(bf16x8*)(&T[r + i * 32][c]) = v;
  }
  __syncthreads();
  for (int i = 0; i < 2; ++i) {
    int dr = r + i * 32;                 // d index
    bf16x8 v;
    for (int j = 0; j < 8; ++j) v[j] = T[c + j][dr];
    *(bf16x8*)(d + (size_t)dr * 1024 + c) = v;
  }
}

// ---------- GEMM body: C[8192,1024] = A[8192,1024](bf16) * BT[1024,1024]^T + bias
static __device__ __forceinline__ void gemm_body(
    const short* __restrict__ A, const short* __restrict__ BT,
    const float* __restrict__ bias, void* __restrict__ Cp, int mode)
{
  __shared__ short As[128 * 64];
  __shared__ short Bs[128 * 64];
  const int K = 1024, N = 1024;
  const int tid = threadIdx.x;
  const int lane = tid & 63, wave = tid >> 6;
  const int quad = lane >> 4, l16 = lane & 15;
  const int wm = (wave & 1) * 64, wn = (wave >> 1) * 64;
  const int bm = blockIdx.x * 128, bn = blockIdx.y * 128;

  f32x4 acc[4][4] = {};

  const int s_row = tid >> 3;            // 0..31
  const int s_col = (tid & 7) * 8;       // 0..56 (shorts)
  const int lds_base = wave * 512;       // wave-uniform (shorts)

  for (int k0 = 0; k0 < K; k0 += 64) {
    for (int i = 0; i < 4; ++i) {
      int row = s_row + i * 32;
      GLDS16(A + (size_t)(bm + row) * K + k0 + s_col, &As[i * 2048 + lds_base]);
      GLDS16(BT + (size_t)(bn + row) * K + k0 + s_col, &Bs[i * 2048 + lds_base]);
    }
    __syncthreads();
    for (int ks = 0; ks < 2; ++ks) {
      bf16x8 af[4], bfr[4];
      for (int mi = 0; mi < 4; ++mi)
        af[mi] = *(const bf16x8*)(&As[(wm + mi * 16 + l16) * 64 + ks * 32 + quad * 8]);
      for (int ni = 0; ni < 4; ++ni)
        bfr[ni] = *(const bf16x8*)(&Bs[(wn + ni * 16 + l16) * 64 + ks * 32 + quad * 8]);
      for (int mi = 0; mi < 4; ++mi)
        for (int ni = 0; ni < 4; ++ni)
          acc[mi][ni] = __builtin_amdgcn_mfma_f32_16x16x32_bf16(af[mi], bfr[ni], acc[mi][ni], 0, 0, 0);
    }
    __syncthreads();
  }

  for (int ni = 0; ni < 4; ++ni) {
    int col = bn + wn + ni * 16 + l16;
    float bv = bias[col];
    for (int mi = 0; mi < 4; ++mi) {
      int row0 = bm + wm + mi * 16 + quad * 4;   // C row = quad*4+reg
      for (int r = 0; r < 4; ++r) {
        int row = row0 + r;
        float fv = acc[mi][ni][r] + bv;
        if (mode == 2) ((float*)Cp)[(size_t)row * N + col] = fv;
        else           ((short*)Cp)[(size_t)row * N + col] = f2bf(fv);
      }
    }
  }
}

__global__ __launch_bounds__(256) void gemm_bt16(
    const short* __restrict__ A, const short* __restrict__ BT,
    const float* __restrict__ bias, void* __restrict__ Cp, int mode)
{
  gemm_body(A, BT, bias, Cp, mode);
}

// combined Q/K/V projection: grid.z selects which GEMM
__global__ __launch_bounds__(256) void gemm_qkv(QkvArgs a)
{
  const int z = blockIdx.z;
  gemm_body(a.A[z], a.B[z], a.bias[z], a.C[z], 0);
}

// ---------- fused attention over [G=128,T=1024,D=64] ----------
// R1 topology + R6 register prefetch + NEW R7 XCD-chunk remap:
// physical block orig round-robins XCDs (xcd = orig%8); work item
// (orig&7)*64 + (orig>>3) gives XCD i exactly batch i's 64 blocks, so
// the per-head 384KB K/V working set stays L2-resident on its XCD.
__global__ __launch_bounds__(256) void attn_fused6(
    const short* __restrict__ Qp, const short* __restrict__ Kp,
    const short* __restrict__ VpT,               // [g][d][t]
    short* __restrict__ ctx,                     // [g][t][d] flat (bf16)
    float* __restrict__ attn_post)               // [b][t][s] FP32
{
  __shared__ short Plds[16][1032];
  __shared__ float red[16][4];
  __shared__ float ctxred[4][16][64];

  const int tid = threadIdx.x;
  const int wave = tid >> 6, lane = tid & 63;
  const int quad = lane >> 4, l16 = lane & 15;
  // XCD-chunk remap (T1): b == orig&7, t-tile == orig>>3
  const int orig = blockIdx.x;
  const int b = orig & 7;
  const int t0 = (orig >> 3) * 16;
  const int sbase = wave * 256;

  float sig[16][4] = {};                         // sigmoid acc over heads

  for (int h = 0; h < 16; ++h) {
    const int g = b * 16 + h;
    const short* Qg = Qp + (size_t)g * 65536;
    const short* Kg = Kp + (size_t)g * 65536;
    const short* Vg = VpT + (size_t)g * 65536;

    bf16x8 aq0 = *(const bf16x8*)(Qg + (t0 + l16) * 64 + quad * 8);
    bf16x8 aq1 = *(const bf16x8*)(Qg + (t0 + l16) * 64 + 32 + quad * 8);

    float sc[16][4];                             // holds e^x
    float rsum[4] = {0.f, 0.f, 0.f, 0.f};

    // ---- QK^T score loop: 16 tiles, K prefetched 4 tiles deep ----
    bf16x8 kb0[4], kb1[4];
#pragma unroll
    for (int t = 0; t < 4; ++t) {
      int s = sbase + t * 16;
      kb0[t] = *(const bf16x8*)(Kg + (s + l16) * 64 + quad * 8);
      kb1[t] = *(const bf16x8*)(Kg + (s + l16) * 64 + 32 + quad * 8);
    }
#pragma unroll
    for (int tile = 0; tile < 16; ++tile) {
      const int slot = tile & 3;
      bf16x8 bk0 = kb0[slot], bk1 = kb1[slot];
      if (tile < 12) {
        int s = sbase + (tile + 4) * 16;
        kb0[slot] = *(const bf16x8*)(Kg + (s + l16) * 64 + quad * 8);
        kb1[slot] = *(const bf16x8*)(Kg + (s + l16) * 64 + 32 + quad * 8);
      }
      f32x4 c = {0.f, 0.f, 0.f, 0.f};
      c = __builtin_amdgcn_mfma_f32_16x16x32_bf16(aq0, bk0, c, 0, 0, 0);
      c = __builtin_amdgcn_mfma_f32_16x16x32_bf16(aq1, bk1, c, 0, 0, 0);
#pragma unroll
      for (int r = 0; r < 4; ++r) {
        float e = exp2_hw(c[r] * L2E_HALF);      // e^(score*0.5)
        sc[tile][r] = e;
        rsum[r] += e;
        sig[tile][r] += e * __builtin_amdgcn_rcpf(1.f + e);   // sigmoid
      }
    }
#pragma unroll
    for (int r = 0; r < 4; ++r)
      for (int mask = 1; mask < 16; mask <<= 1) rsum[r] += __shfl_xor(rsum[r], mask, 64);
    if (l16 == 0)
      for (int r = 0; r < 4; ++r) red[quad * 4 + r][wave] = rsum[r];
    __syncthreads();                             // B1
#pragma unroll
    for (int r = 0; r < 4; ++r) {
      int row = quad * 4 + r;
      float s4 = red[row][0] + red[row][1] + red[row][2] + red[row][3];
      float inv = __builtin_amdgcn_rcpf(s4);
#pragma unroll
      for (int tile = 0; tile < 16; ++tile)
        Plds[row][sbase + tile * 16 + l16] = f2bf_rhu(sc[tile][r] * inv);
    }

    // ---- PV: 8 k-slices, V and P prefetched one slice ahead ----
    f32x4 cacc[4] = {};
    bf16x8 apb[2], vb[2][4];
    apb[0] = *(const bf16x8*)(&Plds[l16][sbase + quad * 8]);
#pragma unroll
    for (int ni = 0; ni < 4; ++ni)
      vb[0][ni] = *(const bf16x8*)(Vg + (ni * 16 + l16) * 1024 + sbase + quad * 8);
#pragma unroll
    for (int ks = 0; ks < 8; ++ks) {
      const int cur = ks & 1, nxt = cur ^ 1;
      if (ks < 7) {
        apb[nxt] = *(const bf16x8*)(&Plds[l16][sbase + (ks + 1) * 32 + quad * 8]);
#pragma unroll
        for (int ni = 0; ni < 4; ++ni)
          vb[nxt][ni] = *(const bf16x8*)(Vg + (ni * 16 + l16) * 1024 + sbase + (ks + 1) * 32 + quad * 8);
      }
#pragma unroll
      for (int ni = 0; ni < 4; ++ni)
        cacc[ni] = __builtin_amdgcn_mfma_f32_16x16x32_bf16(apb[cur], vb[cur][ni], cacc[ni], 0, 0, 0);
    }

    for (int ni = 0; ni < 4; ++ni)
      for (int r = 0; r < 4; ++r)
        ctxred[wave][quad * 4 + r][ni * 16 + l16] = cacc[ni][r];
    __syncthreads();                             // B2
    short* ctxg = ctx + (size_t)g * 65536 + t0 * 64;
    for (int e = tid; e < 1024; e += 256) {
      int t = e >> 6, dd = e & 63;
      float v = ctxred[0][t][dd] + ctxred[1][t][dd] + ctxred[2][t][dd] + ctxred[3][t][dd];
      ctxg[t * 64 + dd] = f2bf(v);
    }
    // red/Plds/ctxred for head h+1 are written only after h+1's B1 -> safe.
  }

  float* ap_out = attn_post + (size_t)b * 1048576 + (size_t)t0 * 1024;
  for (int tile = 0; tile < 16; ++tile)
    for (int r = 0; r < 4; ++r)
      ap_out[(quad * 4 + r) * 1024 + sbase + tile * 16 + l16] = sig[tile][r] * 0.0625f;
}

extern "C" void kernel_launch(void* const* d_in, const int* in_sizes, int n_in,
                              void* d_out, int out_size, void* d_ws, size_t ws_size,
                              hipStream_t stream) {
  const float* query = (const float*)d_in[0];
  const float* key   = (const float*)d_in[1];
  const float* value = (const float*)d_in[2];
  const float* Wq = (const float*)d_in[3]; const float* bq = (const float*)d_in[4];
  const float* Wk = (const float*)d_in[5]; const float* bk = (const float*)d_in[6];
  const float* Wv = (const float*)d_in[7]; const float* bv = (const float*)d_in[8];
  const float* Wo = (const float*)d_in[9]; const float* bo = (const float*)d_in[10];

  float* out0 = (float*)d_out;              // [8,1024,1024] fp32
  float* attn_post = out0 + (8u << 20);     // [8,1024,1024] fp32

  // common workspace head: 4 x 1M weightT + 3 x 8M (Qp,Kp,VpT)
  short* WqT = (short*)d_ws;
  short* WkT = WqT + (1u << 20);
  short* WvT = WkT + (1u << 20);
  short* WoT = WvT + (1u << 20);
  short* Qp  = WoT + (1u << 20);
  short* Kp  = Qp + (8u << 20);
  short* VpT = Kp + (8u << 20);

  dim3 blk(256);
  const size_t NEED_BIG = (size_t)(60u << 20) * 2;   // 120 MiB

  convt4<<<dim3(16, 16, 4), blk, 0, stream>>>(
      Ptr4{{Wq, Wk, Wv, Wo}, {WqT, WkT, WvT, WoT}});

  short* ctx;
  if (ws_size >= NEED_BIG) {
    // big layout: + Xq,Xk,Xv (3 x 8M) + Vflat (8M) = 60M shorts total
    short* Xq = VpT + (8u << 20);
    short* Xk = Xq + (8u << 20);
    short* Xv = Xk + (8u << 20);
    short* Vflat = Xv + (8u << 20);
    ctx = Xq;                                      // dead after qkv GEMM

    cvt3<<<dim3(4096, 1, 3), blk, 0, stream>>>(Ptr3{{query, key, value}, {Xq, Xk, Xv}});
    gemm_qkv<<<dim3(64, 8, 3), blk, 0, stream>>>(
        QkvArgs{{Xq, Xk, Xv}, {WqT, WkT, WvT}, {bq, bk, bv}, {Qp, Kp, Vflat}});
    transp_v<<<dim3(16, 128), blk, 0, stream>>>(Vflat, VpT);
  } else {
    // small layout (88 MB, proven): Xin (8M) + Vflat (8M), sequential
    short* Xin = VpT + (8u << 20);
    short* Vflat = Xin + (8u << 20);
    ctx = Xin;

    cvt3<<<dim3(4096, 1, 1), blk, 0, stream>>>(Ptr3{{query, query, query}, {Xin, Xin, Xin}});
    gemm_bt16<<<dim3(64, 8), blk, 0, stream>>>(Xin, WqT, bq, Qp, 0);
    cvt3<<<dim3(4096, 1, 1), blk, 0, stream>>>(Ptr3{{key, key, key}, {Xin, Xin, Xin}});
    gemm_bt16<<<dim3(64, 8), blk, 0, stream>>>(Xin, WkT, bk, Kp, 0);
    cvt3<<<dim3(4096, 1, 1), blk, 0, stream>>>(Ptr3{{value, value, value}, {Xin, Xin, Xin}});
    gemm_bt16<<<dim3(64, 8), blk, 0, stream>>>(Xin, WvT, bv, Vflat, 0);
    transp_v<<<dim3(16, 128), blk, 0, stream>>>(Vflat, VpT);
  }

  attn_fused6<<<dim3(512), blk, 0, stream>>>(Qp, Kp, VpT, ctx, attn_post);
  gemm_bt16<<<dim3(64, 8), blk, 0, stream>>>(ctx, WoT, bo, out0, 2);
}

// Round 8
// 526.456 us; speedup vs baseline: 1.2704x; 1.0005x over previous
//
#include <hip/hip_runtime.h>

// B=8, S=1024, MD=1024, H=16, D=64. SCALE = (64//16)^-0.5 = 0.5.
// Inputs fp32, OUTPUTS fp32. Internal pipeline bf16 MFMA, fp32 accumulate.
// torch .view(B*H,-1,D) = flat row-major reinterpretation: attention over
// [G=128][T=1024][D=64] with flat pointer math.
//
// R7->R8: locality fixed (FETCH 139->24.6MB) but dur unchanged => latency
// exonerated; the cost is the per-head phase structure. Collapse it:
// (a) deferred normalization -- raw e^x straight to Plds in the score loop
//     (no sc[] register cache, no separate normalize pass);
// (b) d-split PV -- after B1 each wave computes FULL s=1024 PV for its own
//     16 d-columns and writes ctx directly to global (deletes ctxred LDS
//     round-trip, the cross-wave sum pass, and one barrier: 3 -> 2/head);
// (c) PV uses 4 named accumulators (depth-8 chains, not one depth-32).
// XCD batch remap (R7) kept: b = orig&7 (FETCH win is real and free).

typedef __attribute__((ext_vector_type(8))) short bf16x8;
typedef __attribute__((ext_vector_type(4))) float f32x4;

static __device__ __forceinline__ short f2bf(float f) {
  union { float f; unsigned u; } v; v.f = f;
  unsigned lsb = (v.u >> 16) & 1u;
  v.u += 0x7fffu + lsb;
  return (short)(v.u >> 16);
}

// round-half-up bf16 (2 ops); fine for positive e^x values
static __device__ __forceinline__ short f2bf_rhu(float f) {
  union { float f; unsigned u; } v; v.f = f;
  v.u += 0x8000u;
  return (short)(v.u >> 16);
}

// hardware 2^x
static __device__ __forceinline__ float exp2_hw(float x) {
  float r;
  asm("v_exp_f32 %0, %1" : "=v"(r) : "v"(x));
  return r;
}

#define L2E_HALF 0.72134752f   /* 0.5 * log2(e) : e^(score*0.5) = 2^(score*this) */

// async global->LDS, 16B per lane; LDS dest = wave-uniform base + lane*16
#define GLDS16(gp, lp) __builtin_amdgcn_global_load_lds( \
    (const __attribute__((address_space(1))) void*)(gp), \
    (__attribute__((address_space(3))) void*)(lp), 16, 0, 0)

struct Ptr4 { const float* s[4]; short* d[4]; };
struct Ptr3 { const float* s[3]; short* d[3]; };
struct QkvArgs { const short* A[3]; const short* B[3]; const float* bias[3]; short* C[3]; };

// ---------- fp32 W[k][n] -> bf16 WT[n][k], 64x64 tiles; z selects matrix ----
__global__ __launch_bounds__(256) void convt4(Ptr4 a)
{
  const float* __restrict__ src = a.s[blockIdx.z];
  short* __restrict__ dst = a.d[blockIdx.z];
  __shared__ float T[64][65];
  const int tid = threadIdx.x;
  const int c0 = blockIdx.x * 64, r0 = blockIdx.y * 64;
  {
    const int rr = tid >> 4, cc = (tid & 15) * 4;
    for (int i = 0; i < 4; ++i) {
      int row = rr + i * 16;
      const float4 v = *(const float4*)(src + (size_t)(r0 + row) * 1024 + c0 + cc);
      T[row][cc] = v.x; T[row][cc + 1] = v.y; T[row][cc + 2] = v.z; T[row][cc + 3] = v.w;
    }
  }
  __syncthreads();
  {
    const int rr = tid >> 3, cc = (tid & 7) * 8;
    for (int i = 0; i < 2; ++i) {
      int row = rr + i * 32;             // dst row within tile (= src col)
      bf16x8 v;
      for (int j = 0; j < 8; ++j) v[j] = f2bf(T[cc + j][row]);
      *(bf16x8*)(dst + (size_t)(c0 + row) * 1024 + r0 + cc) = v;
    }
  }
}

// ---------- fp32 -> bf16 elementwise; z selects tensor ----------
__global__ __launch_bounds__(256) void cvt3(Ptr3 a)
{
  const float* __restrict__ src = a.s[blockIdx.z];
  short* __restrict__ dst = a.d[blockIdx.z];
  const size_t i = ((size_t)blockIdx.x * 256 + threadIdx.x) * 8;
  const float4 v0 = *(const float4*)(src + i);
  const float4 v1 = *(const float4*)(src + i + 4);
  bf16x8 o;
  o[0] = f2bf(v0.x); o[1] = f2bf(v0.y); o[2] = f2bf(v0.z); o[3] = f2bf(v0.w);
  o[4] = f2bf(v1.x); o[5] = f2bf(v1.y); o[6] = f2bf(v1.z); o[7] = f2bf(v1.w);
  *(bf16x8*)(dst + i) = o;
}

// ---------- per-g 64x64 bf16 tile transpose: V[g][t][d] -> VpT[g][d][t] ----
__global__ __launch_bounds__(256) void transp_v(
    const short* __restrict__ src, short* __restrict__ dst)
{
  __shared__ short T[64][72];
  const int g = blockIdx.y, t0 = blockIdx.x * 64;
  const short* s = src + (size_t)g * 65536 + (size_t)t0 * 64;
  short* d = dst + (size_t)g * 65536 + t0;
  const int r = threadIdx.x >> 3, c = (threadIdx.x & 7) * 8;
  for (int i = 0; i < 2; ++i) {
    bf16x8 v = *(const bf16x8*)(s + (size_t)(r + i * 32) * 64 + c);
    *(bf16x8*)(&T[r + i * 32][c]) = v;
  }
  __syncthreads();
  for (int i = 0; i < 2; ++i) {
    int dr = r + i * 32;                 // d index
    bf16x8 v;
    for (int j = 0; j < 8; ++j) v[j] = T[c + j][dr];
    *(bf16x8*)(d + (size_t)dr * 1024 + c) = v;
  }
}

// ---------- GEMM body: C[8192,1024] = A[8192,1024](bf16) * BT[1024,1024]^T + bias
static __device__ __forceinline__ void gemm_body(
    const short* __restrict__ A, const short* __restrict__ BT,
    const float* __restrict__ bias, void* __restrict__ Cp, int mode)
{
  __shared__ short As[128 * 64];
  __shared__ short Bs[128 * 64];
  const int K = 1024, N = 1024;
  const int tid = threadIdx.x;
  const int lane = tid & 63, wave = tid >> 6;
  const int quad = lane >> 4, l16 = lane & 15;
  const int wm = (wave & 1) * 64, wn = (wave >> 1) * 64;
  const int bm = blockIdx.x * 128, bn = blockIdx.y * 128;

  f32x4 acc[4][4] = {};

  const int s_row = tid >> 3;            // 0..31
  const int s_col = (tid & 7) * 8;       // 0..56 (shorts)
  const int lds_base = wave * 512;       // wave-uniform (shorts)

  for (int k0 = 0; k0 < K; k0 += 64) {
    for (int i = 0; i < 4; ++i) {
      int row = s_row + i * 32;
      GLDS16(A + (size_t)(bm + row) * K + k0 + s_col, &As[i * 2048 + lds_base]);
      GLDS16(BT + (size_t)(bn + row) * K + k0 + s_col, &Bs[i * 2048 + lds_base]);
    }
    __syncthreads();
    for (int ks = 0; ks < 2; ++ks) {
      bf16x8 af[4], bfr[4];
      for (int mi = 0; mi < 4; ++mi)
        af[mi] = *(const bf16x8*)(&As[(wm + mi * 16 + l16) * 64 + ks * 32 + quad * 8]);
      for (int ni = 0; ni < 4; ++ni)
        bfr[ni] = *(const bf16x8*)(&Bs[(wn + ni * 16 + l16) * 64 + ks * 32 + quad * 8]);
      for (int mi = 0; mi < 4; ++mi)
        for (int ni = 0; ni < 4; ++ni)
          acc[mi][ni] = __builtin_amdgcn_mfma_f32_16x16x32_bf16(af[mi], bfr[ni], acc[mi][ni], 0, 0, 0);
    }
    __syncthreads();
  }

  for (int ni = 0; ni < 4; ++ni) {
    int col = bn + wn + ni * 16 + l16;
    float bv = bias[col];
    for (int mi = 0; mi < 4; ++mi) {
      int row0 = bm + wm + mi * 16 + quad * 4;   // C row = quad*4+reg
      for (int r = 0; r < 4; ++r) {
        int row = row0 + r;
        float fv = acc[mi][ni][r] + bv;
        if (mode == 2) ((float*)Cp)[(size_t)row * N + col] = fv;
        else           ((short*)Cp)[(size_t)row * N + col] = f2bf(fv);
      }
    }
  }
}

__global__ __launch_bounds__(256) void gemm_bt16(
    const short* __restrict__ A, const short* __restrict__ BT,
    const float* __restrict__ bias, void* __restrict__ Cp, int mode)
{
  gemm_body(A, BT, bias, Cp, mode);
}

// combined Q/K/V projection: grid.z selects which GEMM
__global__ __launch_bounds__(256) void gemm_qkv(QkvArgs a)
{
  const int z = blockIdx.z;
  gemm_body(a.A[z], a.B[z], a.bias[z], a.C[z], 0);
}

// ---------- fused attention over [G=128,T=1024,D=64] ----------
// block = (b via XCD remap, 16-row t-tile); 4 waves split s for scoring.
// Score phase: raw e^x straight to Plds (deferred normalization), sig in
// regs. B1. PV phase: each wave computes FULL s=1024 for its own 16
// d-columns (A = Plds strip rows l16, B = V^T rows wave*16+l16), scales by
// 1/rsum from red, writes ctx directly to global. B2 guards Plds reuse.
// No max-subtraction: scores*0.5 ~ N(0,16), e^x <= ~e^35 f32-safe, and
// bf16 holds the magnitude fine (relative precision is scale-free).
__global__ __launch_bounds__(256) void attn_fused7(
    const short* __restrict__ Qp, const short* __restrict__ Kp,
    const short* __restrict__ VpT,               // [g][d][t]
    short* __restrict__ ctx,                     // [g][t][d] flat (bf16)
    float* __restrict__ attn_post)               // [b][t][s] FP32
{
  __shared__ short Plds[16][1032];
  __shared__ float red[16][4];

  const int tid = threadIdx.x;
  const int wave = tid >> 6, lane = tid & 63;
  const int quad = lane >> 4, l16 = lane & 15;
  // XCD-chunk remap (T1): b == orig&7, t-tile == orig>>3
  const int orig = blockIdx.x;
  const int b = orig & 7;
  const int t0 = (orig >> 3) * 16;
  const int sbase = wave * 256;

  float sig[16][4] = {};                         // sigmoid acc over heads

  for (int h = 0; h < 16; ++h) {
    const int g = b * 16 + h;
    const short* Qg = Qp + (size_t)g * 65536;
    const short* Kg = Kp + (size_t)g * 65536;
    const short* Vg = VpT + (size_t)g * 65536;

    bf16x8 aq0 = *(const bf16x8*)(Qg + (t0 + l16) * 64 + quad * 8);
    bf16x8 aq1 = *(const bf16x8*)(Qg + (t0 + l16) * 64 + 32 + quad * 8);

    float rsum[4] = {0.f, 0.f, 0.f, 0.f};

    // ---- QK^T score loop: 16 tiles, K prefetched 4 tiles deep ----
    bf16x8 kb0[4], kb1[4];
#pragma unroll
    for (int t = 0; t < 4; ++t) {
      int s = sbase + t * 16;
      kb0[t] = *(const bf16x8*)(Kg + (s + l16) * 64 + quad * 8);
      kb1[t] = *(const bf16x8*)(Kg + (s + l16) * 64 + 32 + quad * 8);
    }
#pragma unroll
    for (int tile = 0; tile < 16; ++tile) {
      const int slot = tile & 3;
      bf16x8 bk0 = kb0[slot], bk1 = kb1[slot];
      if (tile < 12) {
        int s = sbase + (tile + 4) * 16;
        kb0[slot] = *(const bf16x8*)(Kg + (s + l16) * 64 + quad * 8);
        kb1[slot] = *(const bf16x8*)(Kg + (s + l16) * 64 + 32 + quad * 8);
      }
      f32x4 c = {0.f, 0.f, 0.f, 0.f};
      c = __builtin_amdgcn_mfma_f32_16x16x32_bf16(aq0, bk0, c, 0, 0, 0);
      c = __builtin_amdgcn_mfma_f32_16x16x32_bf16(aq1, bk1, c, 0, 0, 0);
#pragma unroll
      for (int r = 0; r < 4; ++r) {
        float e = exp2_hw(c[r] * L2E_HALF);      // e^(score*0.5)
        rsum[r] += e;
        Plds[quad * 4 + r][sbase + tile * 16 + l16] = f2bf_rhu(e);  // RAW e^x
        sig[tile][r] += e * __builtin_amdgcn_rcpf(1.f + e);         // sigmoid
      }
    }
#pragma unroll
    for (int r = 0; r < 4; ++r)
      for (int mask = 1; mask < 16; mask <<= 1) rsum[r] += __shfl_xor(rsum[r], mask, 64);
    if (l16 == 0)
      for (int r = 0; r < 4; ++r) red[quad * 4 + r][wave] = rsum[r];
    __syncthreads();                             // B1: Plds strips + red visible

    // ---- PV: this wave owns d-columns [wave*16, wave*16+16), full s ----
    // A = P[t=l16][s-slice], B = V^T[d=wave*16+l16][s-slice].
    const short* Vw = Vg + (size_t)(wave * 16 + l16) * 1024;
    f32x4 a0 = {0.f,0.f,0.f,0.f}, a1 = a0, a2 = a0, a3 = a0;
#pragma unroll
    for (int sq = 0; sq < 8; ++sq) {
      bf16x8 p0 = *(const bf16x8*)(&Plds[l16][(sq * 4 + 0) * 32 + quad * 8]);
      bf16x8 p1 = *(const bf16x8*)(&Plds[l16][(sq * 4 + 1) * 32 + quad * 8]);
      bf16x8 p2 = *(const bf16x8*)(&Plds[l16][(sq * 4 + 2) * 32 + quad * 8]);
      bf16x8 p3 = *(const bf16x8*)(&Plds[l16][(sq * 4 + 3) * 32 + quad * 8]);
      bf16x8 v0 = *(const bf16x8*)(Vw + (sq * 4 + 0) * 32 + quad * 8);
      bf16x8 v1 = *(const bf16x8*)(Vw + (sq * 4 + 1) * 32 + quad * 8);
      bf16x8 v2 = *(const bf16x8*)(Vw + (sq * 4 + 2) * 32 + quad * 8);
      bf16x8 v3 = *(const bf16x8*)(Vw + (sq * 4 + 3) * 32 + quad * 8);
      a0 = __builtin_amdgcn_mfma_f32_16x16x32_bf16(p0, v0, a0, 0, 0, 0);
      a1 = __builtin_amdgcn_mfma_f32_16x16x32_bf16(p1, v1, a1, 0, 0, 0);
      a2 = __builtin_amdgcn_mfma_f32_16x16x32_bf16(p2, v2, a2, 0, 0, 0);
      a3 = __builtin_amdgcn_mfma_f32_16x16x32_bf16(p3, v3, a3, 0, 0, 0);
    }
    f32x4 cacc;
#pragma unroll
    for (int r = 0; r < 4; ++r) cacc[r] = (a0[r] + a1[r]) + (a2[r] + a3[r]);

    // normalize by 1/rowsum and write ctx directly (lane owns (t,d) fully)
    short* ctxg = ctx + (size_t)g * 65536 + t0 * 64;
#pragma unroll
    for (int r = 0; r < 4; ++r) {
      int row = quad * 4 + r;
      float s4 = red[row][0] + red[row][1] + red[row][2] + red[row][3];
      float inv = __builtin_amdgcn_rcpf(s4);
      ctxg[row * 64 + wave * 16 + l16] = f2bf(cacc[r] * inv);
    }
    __syncthreads();                             // B2: Plds/red free for next head
  }

  float* ap_out = attn_post + (size_t)b * 1048576 + (size_t)t0 * 1024;
  for (int tile = 0; tile < 16; ++tile)
    for (int r = 0; r < 4; ++r)
      ap_out[(quad * 4 + r) * 1024 + sbase + tile * 16 + l16] = sig[tile][r] * 0.0625f;
}

extern "C" void kernel_launch(void* const* d_in, const int* in_sizes, int n_in,
                              void* d_out, int out_size, void* d_ws, size_t ws_size,
                              hipStream_t stream) {
  const float* query = (const float*)d_in[0];
  const float* key   = (const float*)d_in[1];
  const float* value = (const float*)d_in[2];
  const float* Wq = (const float*)d_in[3]; const float* bq = (const float*)d_in[4];
  const float* Wk = (const float*)d_in[5]; const float* bk = (const float*)d_in[6];
  const float* Wv = (const float*)d_in[7]; const float* bv = (const float*)d_in[8];
  const float* Wo = (const float*)d_in[9]; const float* bo = (const float*)d_in[10];

  float* out0 = (float*)d_out;              // [8,1024,1024] fp32
  float* attn_post = out0 + (8u << 20);     // [8,1024,1024] fp32

  // common workspace head: 4 x 1M weightT + 3 x 8M (Qp,Kp,VpT)
  short* WqT = (short*)d_ws;
  short* WkT = WqT + (1u << 20);
  short* WvT = WkT + (1u << 20);
  short* WoT = WvT + (1u << 20);
  short* Qp  = WoT + (1u << 20);
  short* Kp  = Qp + (8u << 20);
  short* VpT = Kp + (8u << 20);

  dim3 blk(256);
  const size_t NEED_BIG = (size_t)(60u << 20) * 2;   // 120 MiB

  convt4<<<dim3(16, 16, 4), blk, 0, stream>>>(
      Ptr4{{Wq, Wk, Wv, Wo}, {WqT, WkT, WvT, WoT}});

  short* ctx;
  if (ws_size >= NEED_BIG) {
    // big layout: + Xq,Xk,Xv (3 x 8M) + Vflat (8M) = 60M shorts total
    short* Xq = VpT + (8u << 20);
    short* Xk = Xq + (8u << 20);
    short* Xv = Xk + (8u << 20);
    short* Vflat = Xv + (8u << 20);
    ctx = Xq;                                      // dead after qkv GEMM

    cvt3<<<dim3(4096, 1, 3), blk, 0, stream>>>(Ptr3{{query, key, value}, {Xq, Xk, Xv}});
    gemm_qkv<<<dim3(64, 8, 3), blk, 0, stream>>>(
        QkvArgs{{Xq, Xk, Xv}, {WqT, WkT, WvT}, {bq, bk, bv}, {Qp, Kp, Vflat}});
    transp_v<<<dim3(16, 128), blk, 0, stream>>>(Vflat, VpT);
  } else {
    // small layout (88 MB, proven): Xin (8M) + Vflat (8M), sequential
    short* Xin = VpT + (8u << 20);
    short* Vflat = Xin + (8u << 20);
    ctx = Xin;

    cvt3<<<dim3(4096, 1, 1), blk, 0, stream>>>(Ptr3{{query, query, query}, {Xin, Xin, Xin}});
    gemm_bt16<<<dim3(64, 8), blk, 0, stream>>>(Xin, WqT, bq, Qp, 0);
    cvt3<<<dim3(4096, 1, 1), blk, 0, stream>>>(Ptr3{{key, key, key}, {Xin, Xin, Xin}});
    gemm_bt16<<<dim3(64, 8), blk, 0, stream>>>(Xin, WkT, bk, Kp, 0);
    cvt3<<<dim3(4096, 1, 1), blk, 0, stream>>>(Ptr3{{value, value, value}, {Xin, Xin, Xin}});
    gemm_bt16<<<dim3(64, 8), blk, 0, stream>>>(Xin, WvT, bv, Vflat, 0);
    transp_v<<<dim3(16, 128), blk, 0, stream>>>(Vflat, VpT);
  }

  attn_fused7<<<dim3(512), blk, 0, stream>>>(Qp, Kp, VpT, ctx, attn_post);
  gemm_bt16<<<dim3(64, 8), blk, 0, stream>>>(ctx, WoT, bo, out0, 2);
}

// Round 9
// 445.705 us; speedup vs baseline: 1.5005x; 1.1812x over previous
//
#include <hip/hip_runtime.h>

// B=8, S=1024, MD=1024, H=16, D=64. SCALE = (64//16)^-0.5 = 0.5.
// Inputs fp32, OUTPUTS fp32. Internal pipeline bf16 MFMA, fp32 accumulate.
// torch .view(B*H,-1,D) = flat row-major reinterpretation: attention over
// [G=128][T=1024][D=64] with flat pointer math.
//
// R8->R9: exonerated by experiment: BW, locality, occupancy, ILP, barriers,
// bank conflicts. Surviving theory: VMEM *instruction* throughput (each
// 16B/lane wave-load = ~16-20cy of the CU's single TA/L1 pipe, shared by
// all waves, identical for L1/L2 hits => explains all nulls). Fix: halve
// VMEM instructions per FLOP. Block now covers t=32 (two t-tiles): each K
// fragment pair feeds 4 MFMA (was 2), each V fragment feeds 2 (was 1).
// Grid 256 = 1 block/CU, 1 wave/SIMD; VALU redistributes onto it
// (launch_bounds(256,1) -> up to 512 VGPR; sig[2][16][4] stays resident).
// Also: XCD swizzle on GEMM grids (XCD i owns N-panel i; bijective).

typedef __attribute__((ext_vector_type(8))) short bf16x8;
typedef __attribute__((ext_vector_type(4))) float f32x4;

static __device__ __forceinline__ short f2bf(float f) {
  union { float f; unsigned u; } v; v.f = f;
  unsigned lsb = (v.u >> 16) & 1u;
  v.u += 0x7fffu + lsb;
  return (short)(v.u >> 16);
}

// round-half-up bf16 (2 ops); fine for positive e^x values
static __device__ __forceinline__ short f2bf_rhu(float f) {
  union { float f; unsigned u; } v; v.f = f;
  v.u += 0x8000u;
  return (short)(v.u >> 16);
}

// hardware 2^x
static __device__ __forceinline__ float exp2_hw(float x) {
  float r;
  asm("v_exp_f32 %0, %1" : "=v"(r) : "v"(x));
  return r;
}

#define L2E_HALF 0.72134752f   /* 0.5 * log2(e) : e^(score*0.5) = 2^(score*this) */

// async global->LDS, 16B per lane; LDS dest = wave-uniform base + lane*16
#define GLDS16(gp, lp) __builtin_amdgcn_global_load_lds( \
    (const __attribute__((address_space(1))) void*)(gp), \
    (__attribute__((address_space(3))) void*)(lp), 16, 0, 0)

struct Ptr4 { const float* s[4]; short* d[4]; };
struct Ptr3 { const float* s[3]; short* d[3]; };
struct QkvArgs { const short* A[3]; const short* B[3]; const float* bias[3]; short* C[3]; };

// ---------- fp32 W[k][n] -> bf16 WT[n][k], 64x64 tiles; z selects matrix ----
__global__ __launch_bounds__(256) void convt4(Ptr4 a)
{
  const float* __restrict__ src = a.s[blockIdx.z];
  short* __restrict__ dst = a.d[blockIdx.z];
  __shared__ float T[64][65];
  const int tid = threadIdx.x;
  const int c0 = blockIdx.x * 64, r0 = blockIdx.y * 64;
  {
    const int rr = tid >> 4, cc = (tid & 15) * 4;
    for (int i = 0; i < 4; ++i) {
      int row = rr + i * 16;
      const float4 v = *(const float4*)(src + (size_t)(r0 + row) * 1024 + c0 + cc);
      T[row][cc] = v.x; T[row][cc + 1] = v.y; T[row][cc + 2] = v.z; T[row][cc + 3] = v.w;
    }
  }
  __syncthreads();
  {
    const int rr = tid >> 3, cc = (tid & 7) * 8;
    for (int i = 0; i < 2; ++i) {
      int row = rr + i * 32;             // dst row within tile (= src col)
      bf16x8 v;
      for (int j = 0; j < 8; ++j) v[j] = f2bf(T[cc + j][row]);
      *(bf16x8*)(dst + (size_t)(c0 + row) * 1024 + r0 + cc) = v;
    }
  }
}

// ---------- fp32 -> bf16 elementwise; z selects tensor ----------
__global__ __launch_bounds__(256) void cvt3(Ptr3 a)
{
  const float* __restrict__ src = a.s[blockIdx.z];
  short* __restrict__ dst = a.d[blockIdx.z];
  const size_t i = ((size_t)blockIdx.x * 256 + threadIdx.x) * 8;
  const float4 v0 = *(const float4*)(src + i);
  const float4 v1 = *(const float4*)(src + i + 4);
  bf16x8 o;
  o[0] = f2bf(v0.x); o[1] = f2bf(v0.y); o[2] = f2bf(v0.z); o[3] = f2bf(v0.w);
  o[4] = f2bf(v1.x); o[5] = f2bf(v1.y); o[6] = f2bf(v1.z); o[7] = f2bf(v1.w);
  *(bf16x8*)(dst + i) = o;
}

// ---------- per-g 64x64 bf16 tile transpose: V[g][t][d] -> VpT[g][d][t] ----
__global__ __launch_bounds__(256) void transp_v(
    const short* __restrict__ src, short* __restrict__ dst)
{
  __shared__ short T[64][72];
  const int g = blockIdx.y, t0 = blockIdx.x * 64;
  const short* s = src + (size_t)g * 65536 + (size_t)t0 * 64;
  short* d = dst + (size_t)g * 65536 + t0;
  const int r = threadIdx.x >> 3, c = (threadIdx.x & 7) * 8;
  for (int i = 0; i < 2; ++i) {
    bf16x8 v = *(const bf16x8*)(s + (size_t)(r + i * 32) * 64 + c);
    *(bf16x8*)(&T[r + i * 32][c]) = v;
  }
  __syncthreads();
  for (int i = 0; i < 2; ++i) {
    int dr = r + i * 32;                 // d index
    bf16x8 v;
    for (int j = 0; j < 8; ++j) v[j] = T[c + j][dr];
    *(bf16x8*)(d + (size_t)dr * 1024 + c) = v;
  }
}

// ---------- GEMM body: C[8192,1024] = A[8192,1024](bf16) * BT[1024,1024]^T + bias
// XCD swizzle (bijective, 512%8==0): dispatch-linear lin = y*64+x round-
// robins XCDs as lin%8; remap so XCD i owns N-panel i (B-panel 256KB stays
// L2-resident per XCD).
static __device__ __forceinline__ void gemm_body(
    const short* __restrict__ A, const short* __restrict__ BT,
    const float* __restrict__ bias, void* __restrict__ Cp, int mode)
{
  __shared__ short As[128 * 64];
  __shared__ short Bs[128 * 64];
  const int K = 1024, N = 1024;
  const int tid = threadIdx.x;
  const int lane = tid & 63, wave = tid >> 6;
  const int quad = lane >> 4, l16 = lane & 15;
  const int wm = (wave & 1) * 64, wn = (wave >> 1) * 64;
  const int lin = blockIdx.y * 64 + blockIdx.x;
  const int bx = (lin >> 3) & 63;        // 0..63 M-tile
  const int by = lin & 7;                // 0..7  N-tile == XCD id
  const int bm = bx * 128, bn = by * 128;

  f32x4 acc[4][4] = {};

  const int s_row = tid >> 3;            // 0..31
  const int s_col = (tid & 7) * 8;       // 0..56 (shorts)
  const int lds_base = wave * 512;       // wave-uniform (shorts)

  for (int k0 = 0; k0 < K; k0 += 64) {
    for (int i = 0; i < 4; ++i) {
      int row = s_row + i * 32;
      GLDS16(A + (size_t)(bm + row) * K + k0 + s_col, &As[i * 2048 + lds_base]);
      GLDS16(BT + (size_t)(bn + row) * K + k0 + s_col, &Bs[i * 2048 + lds_base]);
    }
    __syncthreads();
    for (int ks = 0; ks < 2; ++ks) {
      bf16x8 af[4], bfr[4];
      for (int mi = 0; mi < 4; ++mi)
        af[mi] = *(const bf16x8*)(&As[(wm + mi * 16 + l16) * 64 + ks * 32 + quad * 8]);
      for (int ni = 0; ni < 4; ++ni)
        bfr[ni] = *(const bf16x8*)(&Bs[(wn + ni * 16 + l16) * 64 + ks * 32 + quad * 8]);
      for (int mi = 0; mi < 4; ++mi)
        for (int ni = 0; ni < 4; ++ni)
          acc[mi][ni] = __builtin_amdgcn_mfma_f32_16x16x32_bf16(af[mi], bfr[ni], acc[mi][ni], 0, 0, 0);
    }
    __syncthreads();
  }

  for (int ni = 0; ni < 4; ++ni) {
    int col = bn + wn + ni * 16 + l16;
    float bv = bias[col];
    for (int mi = 0; mi < 4; ++mi) {
      int row0 = bm + wm + mi * 16 + quad * 4;   // C row = quad*4+reg
      for (int r = 0; r < 4; ++r) {
        int row = row0 + r;
        float fv = acc[mi][ni][r] + bv;
        if (mode == 2) ((float*)Cp)[(size_t)row * N + col] = fv;
        else           ((short*)Cp)[(size_t)row * N + col] = f2bf(fv);
      }
    }
  }
}

__global__ __launch_bounds__(256) void gemm_bt16(
    const short* __restrict__ A, const short* __restrict__ BT,
    const float* __restrict__ bias, void* __restrict__ Cp, int mode)
{
  gemm_body(A, BT, bias, Cp, mode);
}

// combined Q/K/V projection: grid.z selects which GEMM
__global__ __launch_bounds__(256) void gemm_qkv(QkvArgs a)
{
  const int z = blockIdx.z;
  gemm_body(a.A[z], a.B[z], a.bias[z], a.C[z], 0);
}

// ---------- fused attention over [G=128,T=1024,D=64] ----------
// block = (b via XCD remap, 32-row t-tile); grid 256 = 1 block/CU.
// Score: 4 waves x s=256 strips; each K fragment pair feeds 2 t-tiles
// (4 MFMA). Raw e^x -> Plds (deferred normalization); sig in regs.
// B1. PV: d-split, wave owns 16 d-cols, full s=1024, V fragment shared by
// both t-tiles; scale by 1/rowsum from red; ctx written straight to
// global. B2 guards Plds reuse. Fragment conventions verbatim from the
// R8-verified kernel, indexed by tt.
__global__ __launch_bounds__(256, 1) void attn_fused8(
    const short* __restrict__ Qp, const short* __restrict__ Kp,
    const short* __restrict__ VpT,               // [g][d][t]
    short* __restrict__ ctx,                     // [g][t][d] flat (bf16)
    float* __restrict__ attn_post)               // [b][t][s] FP32
{
  __shared__ short Plds[32][1032];               // 66KB
  __shared__ float red[32][4];

  const int tid = threadIdx.x;
  const int wave = tid >> 6, lane = tid & 63;
  const int quad = lane >> 4, l16 = lane & 15;
  // XCD-chunk remap (T1): b == orig&7  (XCD i <- batch i)
  const int orig = blockIdx.x;                   // 0..255
  const int b = orig & 7;
  const int t0 = (orig >> 3) * 32;               // 32-row t-tile
  const int sbase = wave * 256;

  float sig[2][16][4] = {};                      // [tt][tile][r]

  for (int h = 0; h < 16; ++h) {
    const int g = b * 16 + h;
    const short* Qg = Qp + (size_t)g * 65536;
    const short* Kg = Kp + (size_t)g * 65536;
    const short* Vg = VpT + (size_t)g * 65536;

    bf16x8 aq[2][2];
#pragma unroll
    for (int tt = 0; tt < 2; ++tt) {
      aq[tt][0] = *(const bf16x8*)(Qg + (t0 + tt * 16 + l16) * 64 + quad * 8);
      aq[tt][1] = *(const bf16x8*)(Qg + (t0 + tt * 16 + l16) * 64 + 32 + quad * 8);
    }

    float rsum[2][4] = {};

    // ---- QK^T score loop: 16 s-tiles, K prefetched 4 tiles deep ----
    bf16x8 kb0[4], kb1[4];
#pragma unroll
    for (int t = 0; t < 4; ++t) {
      int s = sbase + t * 16;
      kb0[t] = *(const bf16x8*)(Kg + (s + l16) * 64 + quad * 8);
      kb1[t] = *(const bf16x8*)(Kg + (s + l16) * 64 + 32 + quad * 8);
    }
#pragma unroll
    for (int tile = 0; tile < 16; ++tile) {
      const int slot = tile & 3;
      bf16x8 bk0 = kb0[slot], bk1 = kb1[slot];
      if (tile < 12) {
        int s = sbase + (tile + 4) * 16;
        kb0[slot] = *(const bf16x8*)(Kg + (s + l16) * 64 + quad * 8);
        kb1[slot] = *(const bf16x8*)(Kg + (s + l16) * 64 + 32 + quad * 8);
      }
#pragma unroll
      for (int tt = 0; tt < 2; ++tt) {
        f32x4 c = {0.f, 0.f, 0.f, 0.f};
        c = __builtin_amdgcn_mfma_f32_16x16x32_bf16(aq[tt][0], bk0, c, 0, 0, 0);
        c = __builtin_amdgcn_mfma_f32_16x16x32_bf16(aq[tt][1], bk1, c, 0, 0, 0);
#pragma unroll
        for (int r = 0; r < 4; ++r) {
          float e = exp2_hw(c[r] * L2E_HALF);    // e^(score*0.5)
          rsum[tt][r] += e;
          Plds[tt * 16 + quad * 4 + r][sbase + tile * 16 + l16] = f2bf_rhu(e);
          sig[tt][tile][r] += e * __builtin_amdgcn_rcpf(1.f + e);   // sigmoid
        }
      }
    }
#pragma unroll
    for (int tt = 0; tt < 2; ++tt)
      for (int r = 0; r < 4; ++r)
        for (int mask = 1; mask < 16; mask <<= 1)
          rsum[tt][r] += __shfl_xor(rsum[tt][r], mask, 64);
    if (l16 == 0)
#pragma unroll
      for (int tt = 0; tt < 2; ++tt)
        for (int r = 0; r < 4; ++r)
          red[tt * 16 + quad * 4 + r][wave] = rsum[tt][r];
    __syncthreads();                             // B1: Plds + red visible

    // ---- PV: wave owns d-cols [wave*16, wave*16+16), full s=1024 ----
    // A = P[t-within-tile = l16][s-slice], B = V^T[d = wave*16+l16][s-slice].
    const short* Vw = Vg + (size_t)(wave * 16 + l16) * 1024;
    f32x4 acc[2][2] = {};                        // [tt][parity]
#pragma unroll
    for (int sl = 0; sl < 32; ++sl) {
      bf16x8 v  = *(const bf16x8*)(Vw + sl * 32 + quad * 8);
      bf16x8 p0 = *(const bf16x8*)(&Plds[l16][sl * 32 + quad * 8]);
      bf16x8 p1 = *(const bf16x8*)(&Plds[16 + l16][sl * 32 + quad * 8]);
      acc[0][sl & 1] = __builtin_amdgcn_mfma_f32_16x16x32_bf16(p0, v, acc[0][sl & 1], 0, 0, 0);
      acc[1][sl & 1] = __builtin_amdgcn_mfma_f32_16x16x32_bf16(p1, v, acc[1][sl & 1], 0, 0, 0);
    }

    // normalize by 1/rowsum and write ctx directly
    short* ctxg = ctx + (size_t)g * 65536 + t0 * 64;
#pragma unroll
    for (int tt = 0; tt < 2; ++tt)
      for (int r = 0; r < 4; ++r) {
        int row = tt * 16 + quad * 4 + r;
        float s4 = red[row][0] + red[row][1] + red[row][2] + red[row][3];
        float inv = __builtin_amdgcn_rcpf(s4);
        float cval = (acc[tt][0][r] + acc[tt][1][r]) * inv;
        ctxg[row * 64 + wave * 16 + l16] = f2bf(cval);
      }
    __syncthreads();                             // B2: Plds/red free for next head
  }

  float* ap_out = attn_post + (size_t)b * 1048576 + (size_t)t0 * 1024;
#pragma unroll
  for (int tt = 0; tt < 2; ++tt)
    for (int tile = 0; tile < 16; ++tile)
      for (int r = 0; r < 4; ++r)
        ap_out[(tt * 16 + quad * 4 + r) * 1024 + sbase + tile * 16 + l16] =
            sig[tt][tile][r] * 0.0625f;
}

extern "C" void kernel_launch(void* const* d_in, const int* in_sizes, int n_in,
                              void* d_out, int out_size, void* d_ws, size_t ws_size,
                              hipStream_t stream) {
  const float* query = (const float*)d_in[0];
  const float* key   = (const float*)d_in[1];
  const float* value = (const float*)d_in[2];
  const float* Wq = (const float*)d_in[3]; const float* bq = (const float*)d_in[4];
  const float* Wk = (const float*)d_in[5]; const float* bk = (const float*)d_in[6];
  const float* Wv = (const float*)d_in[7]; const float* bv = (const float*)d_in[8];
  const float* Wo = (const float*)d_in[9]; const float* bo = (const float*)d_in[10];

  float* out0 = (float*)d_out;              // [8,1024,1024] fp32
  float* attn_post = out0 + (8u << 20);     // [8,1024,1024] fp32

  // common workspace head: 4 x 1M weightT + 3 x 8M (Qp,Kp,VpT)
  short* WqT = (short*)d_ws;
  short* WkT = WqT + (1u << 20);
  short* WvT = WkT + (1u << 20);
  short* WoT = WvT + (1u << 20);
  short* Qp  = WoT + (1u << 20);
  short* Kp  = Qp + (8u << 20);
  short* VpT = Kp + (8u << 20);

  dim3 blk(256);
  const size_t NEED_BIG = (size_t)(60u << 20) * 2;   // 120 MiB

  convt4<<<dim3(16, 16, 4), blk, 0, stream>>>(
      Ptr4{{Wq, Wk, Wv, Wo}, {WqT, WkT, WvT, WoT}});

  short* ctx;
  if (ws_size >= NEED_BIG) {
    // big layout: + Xq,Xk,Xv (3 x 8M) + Vflat (8M) = 60M shorts total
    short* Xq = VpT + (8u << 20);
    short* Xk = Xq + (8u << 20);
    short* Xv = Xk + (8u << 20);
    short* Vflat = Xv + (8u << 20);
    ctx = Xq;                                      // dead after qkv GEMM

    cvt3<<<dim3(4096, 1, 3), blk, 0, stream>>>(Ptr3{{query, key, value}, {Xq, Xk, Xv}});
    gemm_qkv<<<dim3(64, 8, 3), blk, 0, stream>>>(
        QkvArgs{{Xq, Xk, Xv}, {WqT, WkT, WvT}, {bq, bk, bv}, {Qp, Kp, Vflat}});
    transp_v<<<dim3(16, 128), blk, 0, stream>>>(Vflat, VpT);
  } else {
    // small layout (88 MB, proven): Xin (8M) + Vflat (8M), sequential
    short* Xin = VpT + (8u << 20);
    short* Vflat = Xin + (8u << 20);
    ctx = Xin;

    cvt3<<<dim3(4096, 1, 1), blk, 0, stream>>>(Ptr3{{query, query, query}, {Xin, Xin, Xin}});
    gemm_bt16<<<dim3(64, 8), blk, 0, stream>>>(Xin, WqT, bq, Qp, 0);
    cvt3<<<dim3(4096, 1, 1), blk, 0, stream>>>(Ptr3{{key, key, key}, {Xin, Xin, Xin}});
    gemm_bt16<<<dim3(64, 8), blk, 0, stream>>>(Xin, WkT, bk, Kp, 0);
    cvt3<<<dim3(4096, 1, 1), blk, 0, stream>>>(Ptr3{{value, value, value}, {Xin, Xin, Xin}});
    gemm_bt16<<<dim3(64, 8), blk, 0, stream>>>(Xin, WvT, bv, Vflat, 0);
    transp_v<<<dim3(16, 128), blk, 0, stream>>>(Vflat, VpT);
  }

  attn_fused8<<<dim3(256), blk, 0, stream>>>(Qp, Kp, VpT, ctx, attn_post);
  gemm_bt16<<<dim3(64, 8), blk, 0, stream>>>(ctx, WoT, bo, out0, 2);
}